// Round 4
// baseline (81.881 us; speedup 1.0000x reference)
//
#include <hip/hip_runtime.h>
#include <float.h>
#include <math.h>

#define BB 32
#define SS 1024
#define DD 512

typedef float f32x4 __attribute__((ext_vector_type(4)));

// ---------------- K1: fused copy + local_score + xsum partials ----------------
// grid (BB, 32 schunks), 256 threads (4 waves). Each wave handles 8 rows.
__global__ __launch_bounds__(256) void k_main1(
    const float* __restrict__ x, const float* __restrict__ w_score,
    const float* __restrict__ b_score, float* __restrict__ out_x,
    float* __restrict__ local_scores, float* __restrict__ xsum_part)
{
    __shared__ float lds[4 * DD];
    int b = blockIdx.x, sc = blockIdx.y;
    int wave = threadIdx.x >> 6, lane = threadIdx.x & 63;
    int row0 = b * SS + sc * 32 + wave * 8;

    const f32x4* wr = (const f32x4*)w_score;
    f32x4 w0 = wr[lane];
    f32x4 w1 = wr[lane + 64];
    float bs = b_score[0];

    f32x4 acc0 = {0.f, 0.f, 0.f, 0.f}, acc1 = {0.f, 0.f, 0.f, 0.f};

    #pragma unroll
    for (int r = 0; r < 8; ++r) {
        int row = row0 + r;
        const f32x4* xr = (const f32x4*)(x + (size_t)row * DD);
        f32x4*       orow = (f32x4*)(out_x + (size_t)row * DD);
        f32x4 a0 = xr[lane];
        f32x4 a1 = xr[lane + 64];
        __builtin_nontemporal_store(a0, &orow[lane]);
        __builtin_nontemporal_store(a1, &orow[lane + 64]);
        float p = a0.x*w0.x + a0.y*w0.y + a0.z*w0.z + a0.w*w0.w
                + a1.x*w1.x + a1.y*w1.y + a1.z*w1.z + a1.w*w1.w;
        #pragma unroll
        for (int m = 32; m >= 1; m >>= 1) p += __shfl_xor(p, m, 64);
        if (lane == 0) local_scores[row] = p + bs;
        acc0 += a0;
        acc1 += a1;
    }
    // cross-wave column reduce
    f32x4* l4 = (f32x4*)lds;
    l4[wave * 128 + lane]      = acc0;
    l4[wave * 128 + lane + 64] = acc1;
    __syncthreads();
    int tid = threadIdx.x;
    #pragma unroll
    for (int i = 0; i < 2; ++i) {
        int d = tid + i * 256;
        float s = lds[d] + lds[DD + d] + lds[2 * DD + d] + lds[3 * DD + d];
        xsum_part[((size_t)b * 32 + sc) * DD + d] = s;
    }
}

// ---------------- K2: ks partials: ks_part[dc][b][e] ----------------
// grid (8 dchunk, 2 eblock, 4 bgroup), 256 threads.
__global__ __launch_bounds__(256) void k_ks(
    const float* __restrict__ xsum_part, const float* __restrict__ Wk,
    float* __restrict__ ks_part)
{
    __shared__ float xs[8][64];
    int dc = blockIdx.x, eb = blockIdx.y, bg = blockIdx.z;
    int tid = threadIdx.x;
    int e = eb * 256 + tid;
    // load xs[bi][dl] = sum_sc xsum_part[b][sc][d]
    #pragma unroll
    for (int k = 0; k < 2; ++k) {
        int i = tid + k * 256;
        int bi = i >> 6, dl = i & 63;
        int b = bg * 8 + bi, d = dc * 64 + dl;
        float v = 0.f;
        #pragma unroll 8
        for (int scc = 0; scc < 32; ++scc)
            v += xsum_part[((size_t)b * 32 + scc) * DD + d];
        xs[bi][dl] = v;
    }
    __syncthreads();
    float acc[8] = {0,0,0,0,0,0,0,0};
    #pragma unroll 8
    for (int dl = 0; dl < 64; ++dl) {
        float w = Wk[(size_t)(dc * 64 + dl) * DD + e];
        #pragma unroll
        for (int bi = 0; bi < 8; ++bi) acc[bi] += xs[bi][dl] * w;
    }
    #pragma unroll
    for (int bi = 0; bi < 8; ++bi) {
        int b = bg * 8 + bi;
        ks_part[((size_t)dc * BB + b) * DD + e] = acc[bi];
    }
}

// ---------------- K3: v partials + t partials ----------------
// grid (8 echunk, 2 dblock, 4 bgroup), 256 threads.
__global__ __launch_bounds__(256) void k_v(
    const float* __restrict__ ks_part, const float* __restrict__ Wq,
    const float* __restrict__ bq, const float* __restrict__ bk,
    float* __restrict__ v_part, float* __restrict__ t_part)
{
    __shared__ float wq_lds[256 * 65];
    __shared__ float ks_lds[8][64];
    int ec = blockIdx.x, db = blockIdx.y, bg = blockIdx.z;
    int tid = threadIdx.x;
    #pragma unroll
    for (int k = 0; k < 2; ++k) {
        int i = tid + k * 256;
        int bi = i >> 6, el = i & 63;
        int b = bg * 8 + bi, e = ec * 64 + el;
        float val = (float)SS * bk[e];
        #pragma unroll
        for (int dcc = 0; dcc < 8; ++dcc)
            val += ks_part[((size_t)dcc * BB + b) * DD + e];
        ks_lds[bi][el] = val;
    }
    #pragma unroll
    for (int it = 0; it < 16; ++it) {
        int idx = tid + it * 256;          // float4 index
        int rowd = idx >> 4, col4 = idx & 15;
        const f32x4 wv = *(const f32x4*)(Wq + (size_t)(db * 256 + rowd) * DD + ec * 64 + col4 * 4);
        float* dst = &wq_lds[rowd * 65 + col4 * 4];
        dst[0] = wv.x; dst[1] = wv.y; dst[2] = wv.z; dst[3] = wv.w;
    }
    __syncthreads();
    if (db == 0 && tid < 8) {
        float ta = 0.f;
        for (int el = 0; el < 64; ++el) ta += bq[ec * 64 + el] * ks_lds[tid][el];
        t_part[ec * BB + bg * 8 + tid] = ta;
    }
    float acc[8] = {0,0,0,0,0,0,0,0};
    #pragma unroll 8
    for (int el = 0; el < 64; ++el) {
        float wq = wq_lds[tid * 65 + el];
        #pragma unroll
        for (int bi = 0; bi < 8; ++bi) acc[bi] += ks_lds[bi][el] * wq;
    }
    int d = db * 256 + tid;
    #pragma unroll
    for (int bi = 0; bi < 8; ++bi) {
        int b = bg * 8 + bi;
        v_part[((size_t)ec * BB + b) * DD + d] = acc[bi];
    }
}

// ---------------- K4: g_scores[row] = (x[row,:].v[b] + t[b]) / sqrt(D) ----------------
// fuses the v/t partial reduction (v_part is L2-resident, 512 KB)
__global__ __launch_bounds__(256) void k_gscore(
    const float* __restrict__ x, const float* __restrict__ v_part,
    const float* __restrict__ t_part, float* __restrict__ g_scores)
{
    int row  = blockIdx.x * 4 + (threadIdx.x >> 6);
    int lane = threadIdx.x & 63;
    int b = row >> 10;
    f32x4 v0 = {0,0,0,0}, v1 = {0,0,0,0};
    #pragma unroll
    for (int ec = 0; ec < 8; ++ec) {
        const f32x4* vp = (const f32x4*)(v_part + ((size_t)ec * BB + b) * DD);
        v0 += vp[lane];
        v1 += vp[lane + 64];
    }
    const f32x4* xr = (const f32x4*)(x + (size_t)row * DD);
    f32x4 a0 = xr[lane], a1 = xr[lane + 64];
    float sum = a0.x*v0.x + a0.y*v0.y + a0.z*v0.z + a0.w*v0.w
              + a1.x*v1.x + a1.y*v1.y + a1.z*v1.z + a1.w*v1.w;
    #pragma unroll
    for (int m = 32; m >= 1; m >>= 1) sum += __shfl_xor(sum, m, 64);
    if (lane == 0) {
        float t = 0.f;
        #pragma unroll
        for (int ec = 0; ec < 8; ++ec) t += t_part[ec * BB + b];
        g_scores[row] = (sum + t) * 0.04419417382415922f;
    }
}

// ---------------- K5: fused masked dual softmax + context partials ----------------
// grid (BB, 8 schunks), 256 threads. Each block recomputes the per-b softmax
// normalization (cheap, L2-hit) then applies weights to its 128-row chunk.
__global__ __launch_bounds__(256) void k_softmax_context(
    const float* __restrict__ local_scores, const float* __restrict__ g_scores,
    const float* __restrict__ x, const int* __restrict__ x_len,
    const int* __restrict__ slot_idx, const float* __restrict__ beta_raw,
    float* __restrict__ c_part)
{
    __shared__ float red[256];
    __shared__ float w_lds[128];
    int b = blockIdx.x, sc = blockIdx.y, tid = threadIdx.x;
    int len = x_len[b];
    float ls[4], gs[4];
    float lmax = -FLT_MAX, gmax = -FLT_MAX;
    #pragma unroll
    for (int i = 0; i < 4; ++i) {
        int s = tid + i * 256;
        bool valid = s < len;
        ls[i] = valid ? local_scores[b * SS + s] : -FLT_MAX;
        gs[i] = valid ? g_scores[b * SS + s] : -FLT_MAX;
        lmax = fmaxf(lmax, ls[i]);
        gmax = fmaxf(gmax, gs[i]);
    }
    red[tid] = lmax; __syncthreads();
    for (int off = 128; off >= 1; off >>= 1) {
        if (tid < off) red[tid] = fmaxf(red[tid], red[tid + off]);
        __syncthreads();
    }
    lmax = red[0]; __syncthreads();
    red[tid] = gmax; __syncthreads();
    for (int off = 128; off >= 1; off >>= 1) {
        if (tid < off) red[tid] = fmaxf(red[tid], red[tid + off]);
        __syncthreads();
    }
    gmax = red[0]; __syncthreads();

    float lsum = 0.f, gsum = 0.f;
    #pragma unroll
    for (int i = 0; i < 4; ++i) {
        int s = tid + i * 256;
        bool valid = s < len;
        lsum += valid ? expf(ls[i] - lmax) : 0.f;
        gsum += valid ? expf(gs[i] - gmax) : 0.f;
    }
    red[tid] = lsum; __syncthreads();
    for (int off = 128; off >= 1; off >>= 1) {
        if (tid < off) red[tid] += red[tid + off];
        __syncthreads();
    }
    lsum = red[0]; __syncthreads();
    red[tid] = gsum; __syncthreads();
    for (int off = 128; off >= 1; off >>= 1) {
        if (tid < off) red[tid] += red[tid + off];
        __syncthreads();
    }
    gsum = red[0]; __syncthreads();

    float br = beta_raw[slot_idx[0]];
    float beta = 1.f / (1.f + expf(-br));
    float rl = beta / lsum;
    float rg = (1.f - beta) / gsum;

    // weights for this chunk's 128 rows
    if (tid < 128) {
        int s = sc * 128 + tid;
        if (s < len) {
            float l = expf(local_scores[b * SS + s] - lmax);
            float g = expf(g_scores[b * SS + s] - gmax);
            w_lds[tid] = l * rl + g * rg;
        } else {
            w_lds[tid] = 0.f;
        }
    }
    __syncthreads();

    int start = sc * 128;
    int end = min(len, start + 128);
    const float* xb = x + (size_t)b * SS * DD;
    float acc0 = 0.f, acc1 = 0.f;
    #pragma unroll 4
    for (int s = start; s < end; ++s) {
        float w = w_lds[s - start];
        acc0 += w * xb[(size_t)s * DD + tid];
        acc1 += w * xb[(size_t)s * DD + tid + 256];
    }
    c_part[((size_t)sc * BB + b) * DD + tid]       = acc0;
    c_part[((size_t)sc * BB + b) * DD + tid + 256] = acc1;
}

// ---------------- K6: reduce context partials ----------------
__global__ __launch_bounds__(512) void k_context_red(
    const float* __restrict__ c_part, float* __restrict__ out_c)
{
    int b = blockIdx.x, tid = threadIdx.x;
    float s = 0.f;
    #pragma unroll
    for (int sc = 0; sc < 8; ++sc) s += c_part[((size_t)sc * BB + b) * DD + tid];
    out_c[b * DD + tid] = s;
}

extern "C" void kernel_launch(void* const* d_in, const int* in_sizes, int n_in,
                              void* d_out, int out_size, void* d_ws, size_t ws_size,
                              hipStream_t stream) {
    const float* x        = (const float*)d_in[0];
    const int*   x_len    = (const int*)d_in[1];
    const int*   slot_idx = (const int*)d_in[2];
    const float* w_score  = (const float*)d_in[3];
    const float* b_score  = (const float*)d_in[4];
    const float* Wq       = (const float*)d_in[5];
    const float* bq       = (const float*)d_in[6];
    const float* Wk       = (const float*)d_in[7];
    const float* bk       = (const float*)d_in[8];
    const float* beta_raw = (const float*)d_in[9];

    float* out   = (float*)d_out;
    float* out_x = out;                           // [B,S,D]
    float* out_c = out + (size_t)BB * SS * DD;    // [B,D]

    float* ws = (float*)d_ws;
    float* local_scores = ws;                     // 32768
    float* g_scores     = ws + 32768;             // 32768
    float* ks_part      = ws + 65536;             // 8*32*512  = 131072
    float* v_part       = ws + 196608;            // 8*32*512  = 131072
    float* t_part       = ws + 327680;            // 256
    float* xsum_part    = ws + 327936;            // 32*32*512 = 524288
    float* c_part       = xsum_part;              // alias: xsum_part dead after k_ks

    k_main1<<<dim3(BB, 32), 256, 0, stream>>>(x, w_score, b_score, out_x, local_scores, xsum_part);
    k_ks<<<dim3(8, 2, 4), 256, 0, stream>>>(xsum_part, Wk, ks_part);
    k_v<<<dim3(8, 2, 4), 256, 0, stream>>>(ks_part, Wq, bq, bk, v_part, t_part);
    k_gscore<<<BB * SS / 4, 256, 0, stream>>>(x, v_part, t_part, g_scores);
    k_softmax_context<<<dim3(BB, 8), 256, 0, stream>>>(local_scores, g_scores, x, x_len, slot_idx, beta_raw, c_part);
    k_context_red<<<BB, 512, 0, stream>>>(c_part, out_c);
}

// Round 5
// 58.531 us; speedup vs baseline: 1.3989x; 1.3989x over previous
//
#include <hip/hip_runtime.h>
#include <float.h>
#include <math.h>

#define BB 32
#define SS 1024
#define DD 512
#define NCH 32          // chunks per batch (32 rows each)
#define CROWS 32
#define RW 8            // rows per wave

typedef float f32x4 __attribute__((ext_vector_type(4)));

__device__ __forceinline__ float wave_reduce_add(float v) {
    #pragma unroll
    for (int m = 32; m >= 1; m >>= 1) v += __shfl_xor(v, m, 64);
    return v;
}

// ---------------- K1: copy + xsum partials + LOCAL online-softmax chunk partials ----
// grid (BB, NCH), 256 threads = 4 waves x 8 rows. Outputs per (b,chunk):
// xsum_part[512], lP[512] (unnorm weighted x-sum), lm (chunk max), lS (chunk expsum).
__global__ __launch_bounds__(256) void k_pass1(
    const float* __restrict__ x, const float* __restrict__ w_score,
    const int* __restrict__ x_len, float* __restrict__ out_x,
    float* __restrict__ xsum_part, float* __restrict__ lP,
    float* __restrict__ lm, float* __restrict__ lS)
{
    __shared__ float red_xsum[4][DD];
    __shared__ float red_ctx[4][DD];
    __shared__ float m_s[4], S_s[4];
    int b = blockIdx.x, sc = blockIdx.y;
    int wave = threadIdx.x >> 6, lane = threadIdx.x & 63, tid = threadIdx.x;
    int len = x_len[b];
    int s0 = sc * CROWS + wave * RW;
    size_t base = ((size_t)b * SS + s0) * DD;

    const f32x4* wr = (const f32x4*)w_score;
    f32x4 w0 = wr[lane], w1 = wr[lane + 64];

    // batch ALL loads first: 16 float4 in flight per wave (MLP)
    f32x4 a[RW][2];
    #pragma unroll
    for (int r = 0; r < RW; ++r) {
        const f32x4* xr = (const f32x4*)(x + base + (size_t)r * DD);
        a[r][0] = xr[lane];
        a[r][1] = xr[lane + 64];
    }
    #pragma unroll
    for (int r = 0; r < RW; ++r) {
        f32x4* orow = (f32x4*)(out_x + base + (size_t)r * DD);
        __builtin_nontemporal_store(a[r][0], &orow[lane]);
        __builtin_nontemporal_store(a[r][1], &orow[lane + 64]);
    }
    // per-lane dot partials + xsum accumulation (no cross-lane ops yet)
    float p[RW];
    f32x4 acc0 = {0,0,0,0}, acc1 = {0,0,0,0};
    #pragma unroll
    for (int r = 0; r < RW; ++r) {
        f32x4 t0 = a[r][0] * w0 + a[r][1] * w1;
        p[r] = t0.x + t0.y + t0.z + t0.w;
        acc0 += a[r][0];
        acc1 += a[r][1];
    }
    // deferred cross-lane reduces (8 independent butterfly chains)
    #pragma unroll
    for (int r = 0; r < RW; ++r) p[r] = wave_reduce_add(p[r]);
    // wave-local max over valid rows
    float mw = -FLT_MAX;
    #pragma unroll
    for (int r = 0; r < RW; ++r) if (s0 + r < len) mw = fmaxf(mw, p[r]);
    // unnormalized weights (wave-local reference), weighted ctx accumulation
    float Sw = 0.f;
    f32x4 c0 = {0,0,0,0}, c1 = {0,0,0,0};
    #pragma unroll
    for (int r = 0; r < RW; ++r) {
        float wgt = (s0 + r < len) ? __expf(p[r] - mw) : 0.f;
        Sw += wgt;
        c0 += wgt * a[r][0];
        c1 += wgt * a[r][1];
    }
    // cross-wave merge with rescaling
    f32x4* rx = (f32x4*)red_xsum[wave];
    f32x4* rc = (f32x4*)red_ctx[wave];
    rx[lane] = acc0; rx[lane + 64] = acc1;
    rc[lane] = c0;   rc[lane + 64] = c1;
    if (lane == 0) { m_s[wave] = mw; S_s[wave] = Sw; }
    __syncthreads();
    float mc = fmaxf(fmaxf(m_s[0], m_s[1]), fmaxf(m_s[2], m_s[3]));
    float e0 = __expf(m_s[0] - mc), e1 = __expf(m_s[1] - mc);
    float e2 = __expf(m_s[2] - mc), e3 = __expf(m_s[3] - mc);
    #pragma unroll
    for (int i = 0; i < 2; ++i) {
        int d = tid + i * 256;
        size_t off = ((size_t)b * NCH + sc) * DD + d;
        xsum_part[off] = red_xsum[0][d] + red_xsum[1][d] + red_xsum[2][d] + red_xsum[3][d];
        lP[off] = red_ctx[0][d]*e0 + red_ctx[1][d]*e1 + red_ctx[2][d]*e2 + red_ctx[3][d]*e3;
    }
    if (tid == 0) {
        lm[b * NCH + sc] = mc;
        lS[b * NCH + sc] = S_s[0]*e0 + S_s[1]*e1 + S_s[2]*e2 + S_s[3]*e3;
    }
}

// ---------------- K2: ks partials: ks_part[dc][b][e] ----------------
__global__ __launch_bounds__(256) void k_ks(
    const float* __restrict__ xsum_part, const float* __restrict__ Wk,
    float* __restrict__ ks_part)
{
    __shared__ float xs[8][64];
    int dc = blockIdx.x, eb = blockIdx.y, bg = blockIdx.z;
    int tid = threadIdx.x;
    int e = eb * 256 + tid;
    #pragma unroll
    for (int k = 0; k < 2; ++k) {
        int i = tid + k * 256;
        int bi = i >> 6, dl = i & 63;
        int b = bg * 8 + bi, d = dc * 64 + dl;
        float v = 0.f;
        #pragma unroll 8
        for (int scc = 0; scc < NCH; ++scc)
            v += xsum_part[((size_t)b * NCH + scc) * DD + d];
        xs[bi][dl] = v;
    }
    __syncthreads();
    float acc[8] = {0,0,0,0,0,0,0,0};
    #pragma unroll 8
    for (int dl = 0; dl < 64; ++dl) {
        float w = Wk[(size_t)(dc * 64 + dl) * DD + e];
        #pragma unroll
        for (int bi = 0; bi < 8; ++bi) acc[bi] += xs[bi][dl] * w;
    }
    #pragma unroll
    for (int bi = 0; bi < 8; ++bi) {
        int b = bg * 8 + bi;
        ks_part[((size_t)dc * BB + b) * DD + e] = acc[bi];
    }
}

// ---------------- K3: v partials ----------------
__global__ __launch_bounds__(256) void k_v(
    const float* __restrict__ ks_part, const float* __restrict__ Wq,
    const float* __restrict__ bk, float* __restrict__ v_part)
{
    __shared__ float wq_lds[256 * 65];
    __shared__ float ks_lds[8][64];
    int ec = blockIdx.x, db = blockIdx.y, bg = blockIdx.z;
    int tid = threadIdx.x;
    #pragma unroll
    for (int k = 0; k < 2; ++k) {
        int i = tid + k * 256;
        int bi = i >> 6, el = i & 63;
        int b = bg * 8 + bi, e = ec * 64 + el;
        float val = (float)SS * bk[e];
        #pragma unroll
        for (int dcc = 0; dcc < 8; ++dcc)
            val += ks_part[((size_t)dcc * BB + b) * DD + e];
        ks_lds[bi][el] = val;
    }
    #pragma unroll
    for (int it = 0; it < 16; ++it) {
        int idx = tid + it * 256;
        int rowd = idx >> 4, col4 = idx & 15;
        const f32x4 wv = *(const f32x4*)(Wq + (size_t)(db * 256 + rowd) * DD + ec * 64 + col4 * 4);
        float* dst = &wq_lds[rowd * 65 + col4 * 4];
        dst[0] = wv.x; dst[1] = wv.y; dst[2] = wv.z; dst[3] = wv.w;
    }
    __syncthreads();
    float acc[8] = {0,0,0,0,0,0,0,0};
    #pragma unroll 8
    for (int el = 0; el < 64; ++el) {
        float wq = wq_lds[tid * 65 + el];
        #pragma unroll
        for (int bi = 0; bi < 8; ++bi) acc[bi] += ks_lds[bi][el] * wq;
    }
    int d = db * 256 + tid;
    #pragma unroll
    for (int bi = 0; bi < 8; ++bi) {
        int b = bg * 8 + bi;
        v_part[((size_t)ec * BB + b) * DD + d] = acc[bi];
    }
}

// ---------------- K4: g-scores + GLOBAL online-softmax chunk partials ----------------
__global__ __launch_bounds__(256) void k_pass2(
    const float* __restrict__ x, const float* __restrict__ v_part,
    const int* __restrict__ x_len,
    float* __restrict__ gP, float* __restrict__ gm, float* __restrict__ gS)
{
    __shared__ float v_lds[DD];
    __shared__ float red_ctx[4][DD];
    __shared__ float m_s[4], S_s[4];
    int b = blockIdx.x, sc = blockIdx.y;
    int wave = threadIdx.x >> 6, lane = threadIdx.x & 63, tid = threadIdx.x;
    int len = x_len[b];
    int s0 = sc * CROWS + wave * RW;
    size_t base = ((size_t)b * SS + s0) * DD;

    // reduce v_part (8 chunks, L2-resident) into LDS
    #pragma unroll
    for (int i = 0; i < 2; ++i) {
        int d = tid + i * 256;
        float vv = 0.f;
        #pragma unroll
        for (int ec = 0; ec < 8; ++ec) vv += v_part[((size_t)ec * BB + b) * DD + d];
        v_lds[d] = vv;
    }
    __syncthreads();
    const f32x4* vr = (const f32x4*)v_lds;
    f32x4 v0 = vr[lane], v1 = vr[lane + 64];

    f32x4 a[RW][2];
    #pragma unroll
    for (int r = 0; r < RW; ++r) {
        const f32x4* xr = (const f32x4*)(x + base + (size_t)r * DD);
        a[r][0] = xr[lane];
        a[r][1] = xr[lane + 64];
    }
    float p[RW];
    #pragma unroll
    for (int r = 0; r < RW; ++r) {
        f32x4 t0 = a[r][0] * v0 + a[r][1] * v1;
        p[r] = t0.x + t0.y + t0.z + t0.w;
    }
    #pragma unroll
    for (int r = 0; r < RW; ++r)
        p[r] = wave_reduce_add(p[r]) * 0.04419417382415922f;
    float mw = -FLT_MAX;
    #pragma unroll
    for (int r = 0; r < RW; ++r) if (s0 + r < len) mw = fmaxf(mw, p[r]);
    float Sw = 0.f;
    f32x4 c0 = {0,0,0,0}, c1 = {0,0,0,0};
    #pragma unroll
    for (int r = 0; r < RW; ++r) {
        float wgt = (s0 + r < len) ? __expf(p[r] - mw) : 0.f;
        Sw += wgt;
        c0 += wgt * a[r][0];
        c1 += wgt * a[r][1];
    }
    f32x4* rc = (f32x4*)red_ctx[wave];
    rc[lane] = c0; rc[lane + 64] = c1;
    if (lane == 0) { m_s[wave] = mw; S_s[wave] = Sw; }
    __syncthreads();
    float mc = fmaxf(fmaxf(m_s[0], m_s[1]), fmaxf(m_s[2], m_s[3]));
    float e0 = __expf(m_s[0] - mc), e1 = __expf(m_s[1] - mc);
    float e2 = __expf(m_s[2] - mc), e3 = __expf(m_s[3] - mc);
    #pragma unroll
    for (int i = 0; i < 2; ++i) {
        int d = tid + i * 256;
        size_t off = ((size_t)b * NCH + sc) * DD + d;
        gP[off] = red_ctx[0][d]*e0 + red_ctx[1][d]*e1 + red_ctx[2][d]*e2 + red_ctx[3][d]*e3;
    }
    if (tid == 0) {
        gm[b * NCH + sc] = mc;
        gS[b * NCH + sc] = S_s[0]*e0 + S_s[1]*e1 + S_s[2]*e2 + S_s[3]*e3;
    }
}

// ---------------- K5: merge chunk partials, beta-combine ----------------
__global__ __launch_bounds__(512) void k_combine(
    const float* __restrict__ lP, const float* __restrict__ lm, const float* __restrict__ lS,
    const float* __restrict__ gP, const float* __restrict__ gm, const float* __restrict__ gS,
    const int* __restrict__ slot_idx, const float* __restrict__ beta_raw,
    float* __restrict__ out_c)
{
    int b = blockIdx.x, d = threadIdx.x;
    float Ml = -FLT_MAX, Mg = -FLT_MAX;
    #pragma unroll 8
    for (int c = 0; c < NCH; ++c) {
        Ml = fmaxf(Ml, lm[b * NCH + c]);
        Mg = fmaxf(Mg, gm[b * NCH + c]);
    }
    float Sl = 0.f, Pl = 0.f, Sg = 0.f, Pg = 0.f;
    #pragma unroll 4
    for (int c = 0; c < NCH; ++c) {
        float wl = __expf(lm[b * NCH + c] - Ml);
        float wg = __expf(gm[b * NCH + c] - Mg);
        Sl += lS[b * NCH + c] * wl;
        Sg += gS[b * NCH + c] * wg;
        Pl += lP[((size_t)b * NCH + c) * DD + d] * wl;
        Pg += gP[((size_t)b * NCH + c) * DD + d] * wg;
    }
    float br = beta_raw[slot_idx[0]];
    float beta = 1.f / (1.f + __expf(-br));
    out_c[b * DD + d] = beta * Pl / Sl + (1.f - beta) * Pg / Sg;
}

extern "C" void kernel_launch(void* const* d_in, const int* in_sizes, int n_in,
                              void* d_out, int out_size, void* d_ws, size_t ws_size,
                              hipStream_t stream) {
    const float* x        = (const float*)d_in[0];
    const int*   x_len    = (const int*)d_in[1];
    const int*   slot_idx = (const int*)d_in[2];
    const float* w_score  = (const float*)d_in[3];
    // d_in[4] = b_score (softmax shift-invariant, unused)
    const float* Wq       = (const float*)d_in[5];
    // d_in[6] = bq (only affects shift-invariant t, unused)
    const float* Wk       = (const float*)d_in[7];
    const float* bk       = (const float*)d_in[8];
    const float* beta_raw = (const float*)d_in[9];

    float* out   = (float*)d_out;
    float* out_x = out;                           // [B,S,D]
    float* out_c = out + (size_t)BB * SS * DD;    // [B,D]

    float* ws = (float*)d_ws;
    float* ks_part   = ws;                        // 8*32*512   = 131072
    float* v_part    = ws + 131072;               // 8*32*512   = 131072
    float* xsum_part = ws + 262144;               // 32*32*512  = 524288
    float* lP        = ws + 786432;               // 524288
    float* gP        = ws + 1310720;              // 524288
    float* lm        = ws + 1835008;              // 1024
    float* lS        = ws + 1836032;              // 1024
    float* gm        = ws + 1837056;              // 1024
    float* gS        = ws + 1838080;              // 1024

    k_pass1<<<dim3(BB, NCH), 256, 0, stream>>>(x, w_score, x_len, out_x, xsum_part, lP, lm, lS);
    k_ks<<<dim3(8, 2, 4), 256, 0, stream>>>(xsum_part, Wk, ks_part);
    k_v<<<dim3(8, 2, 4), 256, 0, stream>>>(ks_part, Wq, bk, v_part);
    k_pass2<<<dim3(BB, NCH), 256, 0, stream>>>(x, v_part, x_len, gP, gm, gS);
    k_combine<<<BB, 512, 0, stream>>>(lP, lm, lS, gP, gm, gS, slot_idx, beta_raw, out_c);
}